// Round 8
// baseline (152.792 us; speedup 1.0000x reference)
//
#include <hip/hip_runtime.h>

// ShiftVarConv2D: out[n,m,y,x] = sum_{di,dj} coded[n,y+di-1,x+dj-1] *
//                 W[(y%8)*8+(x%8), m, di*3+dj] + bias[g*16+m]
// N=128, H=128, SUB=16 out channels, 3x3 window, weights vary with (y%8,x%8).
//
// R8: exact R4 structure (grid 1024 = n:128 x b1:8, one resident generation,
// 16 m-planes per block, loads AFTER staging so VGPR peak stays under the
// launch_bounds(256,4) cap) + ONLY nontemporal output stores isolated:
// 134 MB of write-once data streams past L2 instead of thrashing it.

#define H 128
#define N_BATCH 128
#define SUB 16

typedef float floatx4 __attribute__((ext_vector_type(4)));

__global__ __launch_bounds__(256, 4) void shiftconv_kernel(
        const float* __restrict__ x,
        const float* __restrict__ w,
        const float* __restrict__ bias,
        float* __restrict__ out) {
    int bid = blockIdx.x;
    int nlo = bid & 7;            // XCD-swizzle: same n -> same XCD
    int q   = bid >> 3;
    int b1  = q & 7;
    int n   = ((q >> 3) << 3) | nlo;

    // Stage + transpose this block's weights: 16 m x 80 floats = 5120 B.
    // ws[m*80 + h*40 + i*4 + jj] = W[oc, tap i], oc = (b1*8+4h+jj)*16 + m;
    // bias at h*40+36+jj. Float4-aligned -> inner loop reads one
    // ds_read_b128 per tap (2-address broadcast, conflict-free).
    __shared__ float ws[16 * 80];
    {
        int t = threadIdx.x;
        if (t < 128) {
            int m  = t >> 3;          // 0..15
            int hh = (t >> 2) & 1;    // 0..1
            int jj = t & 3;           // 0..3
            int oc = (b1 * 8 + 4 * hh + jj) * 16 + m;
            float* dst = ws + m * 80 + hh * 40;
            const float* src = w + oc * 9;
#pragma unroll
            for (int i = 0; i < 9; ++i) dst[i * 4 + jj] = src[i];
            dst[36 + jj] = bias[oc];
        }
    }

    int c  = threadIdx.x & 31;    // x0 = 4c
    int r  = threadIdx.x >> 5;    // 0..7
    int x0 = c << 2;
    int h  = c & 1;               // x0 % 8 == 4h -> b2 = 4h + jj
    int y0 = b1 + (r << 3);       // g=0 row; g=1 row is y0 + 64 (same b1)

    const float* xn = x + (size_t)n * (H * H);

    // in[g][dy][k] = coded[n, yg+dy-1, x0+k-1] (zero padded), k in [0,6)
    // One aligned float4 load per row; halo from neighbor lanes via shuffle.
    float in[2][3][6];
#pragma unroll
    for (int g = 0; g < 2; ++g) {
        int yg = y0 + (g << 6);
#pragma unroll
        for (int dy = 0; dy < 3; ++dy) {
            int ry = yg + dy - 1;
            float4 a = make_float4(0.0f, 0.0f, 0.0f, 0.0f);
            if (ry >= 0 && ry < H) a = *(const float4*)(xn + ry * H + x0);
            in[g][dy][1] = a.x; in[g][dy][2] = a.y;
            in[g][dy][3] = a.z; in[g][dy][4] = a.w;
            float left  = __shfl_up(a.w, 1);    // lane c-1's a.w == row[x0-1]
            float right = __shfl_down(a.x, 1);  // lane c+1's a.x == row[x0+4]
            in[g][dy][0] = (c == 0)  ? 0.0f : left;    // x0-1 < 0 pad
            in[g][dy][5] = (c == 31) ? 0.0f : right;   // x0+4 >= H pad
        }
    }

    __syncthreads();

    float* ob = out + ((size_t)n * SUB) * (H * H) + y0 * H + x0;

#pragma unroll
    for (int mi = 0; mi < 16; ++mi) {
        const float4* wp = (const float4*)(ws + mi * 80 + h * 40);
        float4 b4 = wp[9];                    // bias for jj=0..3
        float a0[4] = {b4.x, b4.y, b4.z, b4.w};
        float a1[4] = {b4.x, b4.y, b4.z, b4.w};
#pragma unroll
        for (int dy = 0; dy < 3; ++dy) {
#pragma unroll
            for (int dj = 0; dj < 3; ++dj) {
                float4 w4 = wp[dy * 3 + dj];  // one ds_read_b128 = 4 weights
                a0[0] = fmaf(in[0][dy][dj + 0], w4.x, a0[0]);
                a0[1] = fmaf(in[0][dy][dj + 1], w4.y, a0[1]);
                a0[2] = fmaf(in[0][dy][dj + 2], w4.z, a0[2]);
                a0[3] = fmaf(in[0][dy][dj + 3], w4.w, a0[3]);
                a1[0] = fmaf(in[1][dy][dj + 0], w4.x, a1[0]);
                a1[1] = fmaf(in[1][dy][dj + 1], w4.y, a1[1]);
                a1[2] = fmaf(in[1][dy][dj + 2], w4.z, a1[2]);
                a1[3] = fmaf(in[1][dy][dj + 3], w4.w, a1[3]);
            }
        }
        // Nontemporal: output is write-once, never re-read -> stream past L2.
        float* p = ob + (size_t)mi * (H * H);
        floatx4 v0 = {a0[0], a0[1], a0[2], a0[3]};
        floatx4 v1 = {a1[0], a1[1], a1[2], a1[3]};
        __builtin_nontemporal_store(v0, (floatx4*)p);
        __builtin_nontemporal_store(v1, (floatx4*)(p + 64 * H));
    }
}

extern "C" void kernel_launch(void* const* d_in, const int* in_sizes, int n_in,
                              void* d_out, int out_size, void* d_ws, size_t ws_size,
                              hipStream_t stream) {
    const float* coded  = (const float*)d_in[0];
    const float* weight = (const float*)d_in[1];
    const float* bias   = (const float*)d_in[2];
    float* out = (float*)d_out;

    shiftconv_kernel<<<N_BATCH * 8, 256, 0, stream>>>(coded, weight, bias, out);
}

// Round 9
// 140.770 us; speedup vs baseline: 1.0854x; 1.0854x over previous
//
#include <hip/hip_runtime.h>

// ShiftVarConv2D: out[n,m,y,x] = sum_{di,dj} coded[n,y+di-1,x+dj-1] *
//                 W[(y%8)*8+(x%8), m, di*3+dj] + bias[g*16+m]
// N=128, H=128, SUB=16 out channels, 3x3 window, weights vary with (y%8,x%8).
//
// R9 = exact R4 revert (best measured: 141.6 us). Session ledger:
//   - DS-read 4x cut, VMEM 3x cut: null (issue side never critical)
//   - store-contiguity (consecutive-row blocks): regression (staging cost)
//   - single-generation merge (this structure): WIN (+4.5 us)
//   - load hoist above staging: regression (VGPR pressure)
//   - nontemporal stores: regression (bypasses L2 write-combining)
// Remaining window = harness poison fills (~103 us) + ~22 us write roofline
// + mixed-stream/launch overhead; no counter-supported lever remains.
//
// Structure: grid 1024 = (n:128, b1:8), XCD-swizzled, exactly 4 blocks/CU =
// one resident generation. Each block: all 16 m-planes for its 16 rows
// (y = b1+8r and +64, same y%8 -> same weights). Weights transposed into
// 5 KB LDS tap-major so each tap is one ds_read_b128 (2-addr broadcast,
// conflict-free). Input: one aligned float4 load per row, halo via __shfl.
// Stores: wave-contiguous 512 B segments, plain write-back path.

#define H 128
#define N_BATCH 128
#define SUB 16

__global__ __launch_bounds__(256, 4) void shiftconv_kernel(
        const float* __restrict__ x,
        const float* __restrict__ w,
        const float* __restrict__ bias,
        float* __restrict__ out) {
    int bid = blockIdx.x;
    int nlo = bid & 7;            // XCD-swizzle: same n -> same XCD
    int q   = bid >> 3;
    int b1  = q & 7;
    int n   = ((q >> 3) << 3) | nlo;

    // Stage + transpose this block's weights: 16 m x 80 floats = 5120 B.
    // ws[m*80 + h*40 + i*4 + jj] = W[oc, tap i], oc = (b1*8+4h+jj)*16 + m;
    // bias at h*40+36+jj.
    __shared__ float ws[16 * 80];
    {
        int t = threadIdx.x;
        if (t < 128) {
            int m  = t >> 3;          // 0..15
            int hh = (t >> 2) & 1;    // 0..1
            int jj = t & 3;           // 0..3
            int oc = (b1 * 8 + 4 * hh + jj) * 16 + m;
            float* dst = ws + m * 80 + hh * 40;
            const float* src = w + oc * 9;
#pragma unroll
            for (int i = 0; i < 9; ++i) dst[i * 4 + jj] = src[i];
            dst[36 + jj] = bias[oc];
        }
    }

    int c  = threadIdx.x & 31;    // x0 = 4c
    int r  = threadIdx.x >> 5;    // 0..7
    int x0 = c << 2;
    int h  = c & 1;               // x0 % 8 == 4h -> b2 = 4h + jj
    int y0 = b1 + (r << 3);       // g=0 row; g=1 row is y0 + 64 (same b1)

    const float* xn = x + (size_t)n * (H * H);

    // in[g][dy][k] = coded[n, yg+dy-1, x0+k-1] (zero padded), k in [0,6)
    // One aligned float4 load per row; halo from neighbor lanes via shuffle.
    float in[2][3][6];
#pragma unroll
    for (int g = 0; g < 2; ++g) {
        int yg = y0 + (g << 6);
#pragma unroll
        for (int dy = 0; dy < 3; ++dy) {
            int ry = yg + dy - 1;
            float4 a = make_float4(0.0f, 0.0f, 0.0f, 0.0f);
            if (ry >= 0 && ry < H) a = *(const float4*)(xn + ry * H + x0);
            in[g][dy][1] = a.x; in[g][dy][2] = a.y;
            in[g][dy][3] = a.z; in[g][dy][4] = a.w;
            float left  = __shfl_up(a.w, 1);    // lane c-1's a.w == row[x0-1]
            float right = __shfl_down(a.x, 1);  // lane c+1's a.x == row[x0+4]
            in[g][dy][0] = (c == 0)  ? 0.0f : left;    // x0-1 < 0 pad
            in[g][dy][5] = (c == 31) ? 0.0f : right;   // x0+4 >= H pad
        }
    }

    __syncthreads();

    float* ob = out + ((size_t)n * SUB) * (H * H) + y0 * H + x0;

#pragma unroll
    for (int mi = 0; mi < 16; ++mi) {
        const float4* wp = (const float4*)(ws + mi * 80 + h * 40);
        float4 b4 = wp[9];                    // bias for jj=0..3
        float a0[4] = {b4.x, b4.y, b4.z, b4.w};
        float a1[4] = {b4.x, b4.y, b4.z, b4.w};
#pragma unroll
        for (int dy = 0; dy < 3; ++dy) {
#pragma unroll
            for (int dj = 0; dj < 3; ++dj) {
                float4 w4 = wp[dy * 3 + dj];  // one ds_read_b128 = 4 weights
                a0[0] = fmaf(in[0][dy][dj + 0], w4.x, a0[0]);
                a0[1] = fmaf(in[0][dy][dj + 1], w4.y, a0[1]);
                a0[2] = fmaf(in[0][dy][dj + 2], w4.z, a0[2]);
                a0[3] = fmaf(in[0][dy][dj + 3], w4.w, a0[3]);
                a1[0] = fmaf(in[1][dy][dj + 0], w4.x, a1[0]);
                a1[1] = fmaf(in[1][dy][dj + 1], w4.y, a1[1]);
                a1[2] = fmaf(in[1][dy][dj + 2], w4.z, a1[2]);
                a1[3] = fmaf(in[1][dy][dj + 3], w4.w, a1[3]);
            }
        }
        float* p = ob + (size_t)mi * (H * H);
        *(float4*)(p)          = make_float4(a0[0], a0[1], a0[2], a0[3]);
        *(float4*)(p + 64 * H) = make_float4(a1[0], a1[1], a1[2], a1[3]);
    }
}

extern "C" void kernel_launch(void* const* d_in, const int* in_sizes, int n_in,
                              void* d_out, int out_size, void* d_ws, size_t ws_size,
                              hipStream_t stream) {
    const float* coded  = (const float*)d_in[0];
    const float* weight = (const float*)d_in[1];
    const float* bias   = (const float*)d_in[2];
    float* out = (float*)d_out;

    shiftconv_kernel<<<N_BATCH * 8, 256, 0, stream>>>(coded, weight, bias, out);
}